// Round 4
// baseline (157.322 us; speedup 1.0000x reference)
//
#include <hip/hip_runtime.h>
#include <hip/hip_bf16.h>
#include <math.h>

typedef __attribute__((ext_vector_type(4))) float f32x4;
typedef __bf16 bf16x8 __attribute__((ext_vector_type(8)));
typedef unsigned short u16;
typedef void __attribute__((address_space(1))) * as1p;
typedef void __attribute__((address_space(3))) * as3p;

__device__ __forceinline__ unsigned short f2bf(float f) {
    union { float f; unsigned int u; } v; v.f = f;
    unsigned int u = v.u;
    u += 0x7fffu + ((u >> 16) & 1u);   // RNE
    return (unsigned short)(u >> 16);
}

__device__ __forceinline__ float bf2f(unsigned short b) {
    union { unsigned int u; float f; } v;
    v.u = ((unsigned int)b) << 16;
    return v.f;
}

__device__ __forceinline__ float fast_tanh(float v) {
    float vc = fminf(fmaxf(v, -15.f), 15.f);
    float e = __expf(2.f * vc);
    return (e - 1.f) / (e + 1.f);
}

// ---------- prepass: fp32 -> bf16 for X, h_prev ----------
__global__ void cvt_xh(const float* __restrict__ x, const float* __restrict__ h,
                       u16* __restrict__ xb, u16* __restrict__ hb, int n4) {
    int i = blockIdx.x * blockDim.x + threadIdx.x;
    int stride = gridDim.x * blockDim.x;
    const float4* x4 = (const float4*)x;
    const float4* h4 = (const float4*)h;
    ushort4* xb4 = (ushort4*)xb;
    ushort4* hb4 = (ushort4*)hb;
    for (; i < n4; i += stride) {
        float4 v = x4[i];
        xb4[i] = make_ushort4(f2bf(v.x), f2bf(v.y), f2bf(v.z), f2bf(v.w));
        float4 w = h4[i];
        hb4[i] = make_ushort4(f2bf(w.x), f2bf(w.y), f2bf(w.z), f2bf(w.w));
    }
}

// ---------- prepass: transpose+convert weight fp32 [1024][512] -> bf16 [512][1024] ----------
__global__ void tr_cvt(const float* __restrict__ src, u16* __restrict__ dst) {
    __shared__ float t[32][33];
    int n0 = blockIdx.x * 32;
    int k0 = blockIdx.y * 32;
    int tx = threadIdx.x, ty = threadIdx.y;
#pragma unroll
    for (int i = 0; i < 4; ++i)
        t[ty + i * 8][tx] = src[(size_t)(k0 + ty + i * 8) * 512 + n0 + tx];
    __syncthreads();
#pragma unroll
    for (int i = 0; i < 4; ++i)
        dst[(size_t)(n0 + ty + i * 8) * 1024 + k0 + tx] = f2bf(t[tx][ty + i * 8]);
}

// ---------- m97-style staging: linear 128x64 bf16 tile via global_load_lds(16B) ----------
__device__ __forceinline__ void stage128x64_lin(const u16* g, int gstride,
                                                u16* lds, int tid) {
    int w = tid >> 6;
    int l = tid & 63;
#pragma unroll
    for (int i = 0; i < 4; ++i) {
        int o = i * 4096 + w * 1024 + l * 16;
        int row = o >> 7;
        int ke = (o & 127) >> 1;
        const u16* gp = g + (size_t)row * gstride + ke;
        u16* lp = lds + ((i * 4096 + w * 1024) >> 1);  // wave-uniform base; HW adds lane*16
        __builtin_amdgcn_global_load_lds((as1p)(void*)gp, (as3p)(void*)lp, 16, 0, 0);
    }
}

// ================= gemm1: m97 128x128, XCD-swizzled, [X|H] @ [Wz|Wr]^T =================
// epilogue: col<512 -> zgb = bf16(sigmoid(.+ub)); else rgh = bf16(sigmoid(.+rb)*h) using bf16 Hb
__global__ __launch_bounds__(256) void gemm1_k(
    const u16* __restrict__ Xb, const u16* __restrict__ Hb, const u16* __restrict__ Wt,
    const float* __restrict__ ub, const float* __restrict__ rb_,
    u16* __restrict__ zgb, u16* __restrict__ rgh) {
    __shared__ u16 ldsA[128 * 64];
    __shared__ u16 ldsB[128 * 64];
    int tid = threadIdx.x;
    int l = tid & 63, w = tid >> 6;
    int wr = w >> 1, wc = w & 1;
    int bidl = blockIdx.x;                       // 0..1023
    int swz = (bidl & 7) * 128 + (bidl >> 3);    // bijective XCD swizzle (1024 % 8 == 0)
    int mb = swz >> 3, nb = swz & 7;
    int m0 = mb * 128;
    int n0 = nb * 128;
    f32x4 acc[4][4];
#pragma unroll
    for (int m = 0; m < 4; ++m)
#pragma unroll
        for (int n = 0; n < 4; ++n) acc[m][n] = (f32x4){0.f, 0.f, 0.f, 0.f};

    int fr = l & 15;
    int fk = (l >> 4) << 3;

    for (int k0 = 0; k0 < 1024; k0 += 64) {
        const u16* gA = (k0 < 512) ? (Xb + (size_t)m0 * 512 + k0)
                                   : (Hb + (size_t)m0 * 512 + (k0 - 512));
        stage128x64_lin(gA, 512, ldsA, tid);
        stage128x64_lin(Wt + (size_t)n0 * 1024 + k0, 1024, ldsB, tid);
        __syncthreads();
#pragma unroll
        for (int kk = 0; kk < 64; kk += 32) {
            bf16x8 a[4], b[4];
#pragma unroll
            for (int m = 0; m < 4; ++m)
                a[m] = *(const bf16x8*)&ldsA[(wr * 64 + m * 16 + fr) * 64 + kk + fk];
#pragma unroll
            for (int n = 0; n < 4; ++n)
                b[n] = *(const bf16x8*)&ldsB[(wc * 64 + n * 16 + fr) * 64 + kk + fk];
#pragma unroll
            for (int m = 0; m < 4; ++m)
#pragma unroll
                for (int n = 0; n < 4; ++n)
                    acc[m][n] = __builtin_amdgcn_mfma_f32_16x16x32_bf16(a[m], b[n], acc[m][n], 0, 0, 0);
        }
        __syncthreads();
    }

    int colb = n0 + wc * 64;
    int rowb = m0 + wr * 64 + ((l >> 4) << 2);
#pragma unroll
    for (int n = 0; n < 4; ++n) {
        int col = colb + n * 16 + (l & 15);
        bool isZ = col < 512;
        int c = col & 511;
        float bias = isZ ? ub[c] : rb_[c];
#pragma unroll
        for (int m = 0; m < 4; ++m) {
            int row0 = rowb + m * 16;
#pragma unroll
            for (int r = 0; r < 4; ++r) {
                int row = row0 + r;
                float v = acc[m][n][r] + bias;
                float s = 1.f / (1.f + __expf(-v));
                if (isZ) zgb[(size_t)row * 512 + c] = f2bf(s);
                else     rgh[(size_t)row * 512 + c] = f2bf(s * bf2f(Hb[(size_t)row * 512 + c]));
            }
        }
    }
}

// ================= gemm2: m97 128x128 (as round 3), zg now bf16 =================
__global__ __launch_bounds__(256) void gemm2_k(
    const u16* __restrict__ Xb, const u16* __restrict__ rgh, const u16* __restrict__ Wt,
    const float* __restrict__ hp, const u16* __restrict__ zgb, const float* __restrict__ hb,
    float* __restrict__ out) {
    __shared__ u16 ldsA[128 * 64];
    __shared__ u16 ldsB[128 * 64];
    int tid = threadIdx.x;
    int l = tid & 63, w = tid >> 6;
    int wr = w >> 1, wc = w & 1;
    int bidl = blockIdx.y * 4 + blockIdx.x;          // 0..511
    int swz = (bidl & 7) * 64 + (bidl >> 3);         // bijective XCD swizzle
    int mb = swz >> 2, nb = swz & 3;
    int m0 = mb * 128;
    int n0 = nb * 128;
    f32x4 acc[4][4];
#pragma unroll
    for (int m = 0; m < 4; ++m)
#pragma unroll
        for (int n = 0; n < 4; ++n) acc[m][n] = (f32x4){0.f, 0.f, 0.f, 0.f};

    int fr = l & 15;
    int fk = (l >> 4) << 3;

    for (int k0 = 0; k0 < 1024; k0 += 64) {
        const u16* gA = (k0 < 512) ? (Xb + (size_t)m0 * 512 + k0)
                                   : (rgh + (size_t)m0 * 512 + (k0 - 512));
        stage128x64_lin(gA, 512, ldsA, tid);
        stage128x64_lin(Wt + (size_t)n0 * 1024 + k0, 1024, ldsB, tid);
        __syncthreads();
#pragma unroll
        for (int kk = 0; kk < 64; kk += 32) {
            bf16x8 a[4], b[4];
#pragma unroll
            for (int m = 0; m < 4; ++m)
                a[m] = *(const bf16x8*)&ldsA[(wr * 64 + m * 16 + fr) * 64 + kk + fk];
#pragma unroll
            for (int n = 0; n < 4; ++n)
                b[n] = *(const bf16x8*)&ldsB[(wc * 64 + n * 16 + fr) * 64 + kk + fk];
#pragma unroll
            for (int m = 0; m < 4; ++m)
#pragma unroll
                for (int n = 0; n < 4; ++n)
                    acc[m][n] = __builtin_amdgcn_mfma_f32_16x16x32_bf16(a[m], b[n], acc[m][n], 0, 0, 0);
        }
        __syncthreads();
    }

    int colb = n0 + wc * 64;
    int rowb = m0 + wr * 64 + ((l >> 4) << 2);
#pragma unroll
    for (int n = 0; n < 4; ++n) {
        int col = colb + n * 16 + (l & 15);
        float bias = hb[col];
#pragma unroll
        for (int m = 0; m < 4; ++m) {
            int row0 = rowb + m * 16;
#pragma unroll
            for (int r = 0; r < 4; ++r) {
                int row = row0 + r;
                float v = acc[m][n][r] + bias;
                float t = fast_tanh(v);
                float h0 = hp[(size_t)row * 512 + col];
                float z = bf2f(zgb[(size_t)row * 512 + col]);
                out[(size_t)row * 512 + col] = h0 + z * (t - h0);
            }
        }
    }
}

extern "C" void kernel_launch(void* const* d_in, const int* in_sizes, int n_in,
                              void* d_out, int out_size, void* d_ws, size_t ws_size,
                              hipStream_t stream) {
    const float* x  = (const float*)d_in[0];
    const float* h  = (const float*)d_in[1];
    const float* wz = (const float*)d_in[2];
    const float* wr = (const float*)d_in[3];
    const float* wh = (const float*)d_in[4];
    const float* ub = (const float*)d_in[5];
    const float* rb = (const float*)d_in[6];
    const float* hb = (const float*)d_in[7];
    float* out = (float*)d_out;

    const int B = 16384;
    char* ws = (char*)d_ws;
    size_t off = 0;
    u16* Xb  = (u16*)(ws + off); off += (size_t)B * 512 * 2;      // 16 MB
    u16* Hb  = (u16*)(ws + off); off += (size_t)B * 512 * 2;      // 16 MB
    u16* Wzr = (u16*)(ws + off); off += (size_t)1024 * 1024 * 2;  // 2 MB
    u16* Wht = (u16*)(ws + off); off += (size_t)512 * 1024 * 2;   // 1 MB
    u16* rgh = (u16*)(ws + off); off += (size_t)B * 512 * 2;      // 16 MB
    u16* zgb = (u16*)(ws + off); off += (size_t)B * 512 * 2;      // 16 MB

    cvt_xh<<<2048, 256, 0, stream>>>(x, h, Xb, Hb, B * 512 / 4);

    dim3 tb(32, 8), tg(16, 32);
    tr_cvt<<<tg, tb, 0, stream>>>(wz, Wzr);
    tr_cvt<<<tg, tb, 0, stream>>>(wr, Wzr + (size_t)512 * 1024);
    tr_cvt<<<tg, tb, 0, stream>>>(wh, Wht);

    gemm1_k<<<1024, 256, 0, stream>>>(Xb, Hb, Wzr, ub, rb, zgb, rgh);
    gemm2_k<<<dim3(4, 128), 256, 0, stream>>>(Xb, rgh, Wht, h, zgb, hb, out);
}

// Round 5
// 119.344 us; speedup vs baseline: 1.3182x; 1.3182x over previous
//
#include <hip/hip_runtime.h>
#include <hip/hip_bf16.h>
#include <math.h>

typedef __attribute__((ext_vector_type(4))) float f32x4;
typedef __bf16 bf16x8 __attribute__((ext_vector_type(8)));
typedef unsigned short u16;
typedef void __attribute__((address_space(1))) * as1p;
typedef void __attribute__((address_space(3))) * as3p;

__device__ __forceinline__ unsigned short f2bf(float f) {
    union { float f; unsigned int u; } v; v.f = f;
    unsigned int u = v.u;
    u += 0x7fffu + ((u >> 16) & 1u);   // RNE
    return (unsigned short)(u >> 16);
}

__device__ __forceinline__ float bf2f(unsigned short b) {
    union { unsigned int u; float f; } v;
    v.u = ((unsigned int)b) << 16;
    return v.f;
}

__device__ __forceinline__ float fast_tanh(float v) {
    float vc = fminf(fmaxf(v, -15.f), 15.f);
    float e = __expf(2.f * vc);
    return (e - 1.f) / (e + 1.f);
}

// ---------- prepass: fp32 -> bf16 for X, h_prev ----------
__global__ void cvt_xh(const float* __restrict__ x, const float* __restrict__ h,
                       u16* __restrict__ xb, u16* __restrict__ hb, int n4) {
    int i = blockIdx.x * blockDim.x + threadIdx.x;
    int stride = gridDim.x * blockDim.x;
    const float4* x4 = (const float4*)x;
    const float4* h4 = (const float4*)h;
    ushort4* xb4 = (ushort4*)xb;
    ushort4* hb4 = (ushort4*)hb;
    for (; i < n4; i += stride) {
        float4 v = x4[i];
        xb4[i] = make_ushort4(f2bf(v.x), f2bf(v.y), f2bf(v.z), f2bf(v.w));
        float4 w = h4[i];
        hb4[i] = make_ushort4(f2bf(w.x), f2bf(w.y), f2bf(w.z), f2bf(w.w));
    }
}

// ---------- prepass: 3 weight transposes in one launch (blockIdx.z selects) ----------
__global__ void tr_cvt3(const float* __restrict__ s0, const float* __restrict__ s1,
                        const float* __restrict__ s2, u16* __restrict__ d0,
                        u16* __restrict__ d1, u16* __restrict__ d2) {
    __shared__ float t[32][33];
    const float* src = (blockIdx.z == 0) ? s0 : (blockIdx.z == 1) ? s1 : s2;
    u16* dst = (blockIdx.z == 0) ? d0 : (blockIdx.z == 1) ? d1 : d2;
    int n0 = blockIdx.x * 32;
    int k0 = blockIdx.y * 32;
    int tx = threadIdx.x, ty = threadIdx.y;
#pragma unroll
    for (int i = 0; i < 4; ++i)
        t[ty + i * 8][tx] = src[(size_t)(k0 + ty + i * 8) * 512 + n0 + tx];
    __syncthreads();
#pragma unroll
    for (int i = 0; i < 4; ++i)
        dst[(size_t)(n0 + ty + i * 8) * 1024 + k0 + tx] = f2bf(t[tx][ty + i * 8]);
}

// ---------- staging: 128x64 bf16 tile, linear LDS dest, inverse-swizzled source ----------
// (both-sides-or-neither pairing with ld_frag below; pair validated in round 2: conflicts=0, correct)
__device__ __forceinline__ void stage_sw(const u16* g, int gstride, u16* lds, int tid) {
#pragma unroll
    for (int i = 0; i < 4; ++i) {
        int ob = i * 4096 + ((tid >> 6) << 10);     // wave-uniform byte base
        int o = ob + ((tid & 63) << 4);             // this lane's dest byte
        int row = o >> 7;
        int cb = (o & 127) ^ ((row & 7) << 4);      // inverse-swizzled source bytes
        const u16* gp = g + (size_t)row * gstride + (cb >> 1);
        __builtin_amdgcn_global_load_lds((as1p)(void*)gp, (as3p)(void*)(lds + (ob >> 1)), 16, 0, 0);
    }
}

// ---------- swizzled LDS fragment read ----------
__device__ __forceinline__ bf16x8 ld_frag(const u16* region, int r, int kb) {
    int byte = (r << 7) + (kb ^ ((r & 7) << 4));
    return *(const bf16x8*)((const char*)region + byte);
}

// ---------- one K-step's compute: 8 swizzled ds_read_b128 + 16 MFMA per kk-half ----------
__device__ __forceinline__ void compute_tile(const u16* LA, const u16* LB,
                                             int wr, int wc, int l, f32x4 (&acc)[4][4]) {
    int fr = l & 15;
    int kbb = (l >> 4) << 4;   // byte offset of this lane's k-group
#pragma unroll
    for (int q = 0; q < 2; ++q) {
        bf16x8 a[4], b[4];
#pragma unroll
        for (int m = 0; m < 4; ++m)
            a[m] = ld_frag(LA, wr * 64 + m * 16 + fr, q * 64 + kbb);
#pragma unroll
        for (int n = 0; n < 4; ++n)
            b[n] = ld_frag(LB, wc * 64 + n * 16 + fr, q * 64 + kbb);
#pragma unroll
        for (int m = 0; m < 4; ++m)
#pragma unroll
            for (int n = 0; n < 4; ++n)
                acc[m][n] = __builtin_amdgcn_mfma_f32_16x16x32_bf16(a[m], b[n], acc[m][n], 0, 0, 0);
    }
}

// ---------- 2-phase prefetch K-loop (T3-minimum): stage(t+1) BEFORE compute(t) ----------
// LDS: 2 buffers x (A 16KB + B 16KB) = 64 KB -> 2 blocks/CU.
template<typename AF, typename BF>
__device__ __forceinline__ void kloop(AF ga, BF gb, u16* lds, int tid,
                                      int wr, int wc, int l, f32x4 (&acc)[4][4]) {
    // buffer b: A at lds + b*16384, B at lds + b*16384 + 8192 (element offsets)
    stage_sw(ga(0), 512, lds, tid);
    stage_sw(gb(0), 1024, lds + 8192, tid);
    __syncthreads();
#pragma unroll
    for (int i = 0; i < 15; ++i) {
        u16* nxt = lds + ((i + 1) & 1) * 16384;
        const u16* cur = lds + (i & 1) * 16384;
        stage_sw(ga(i + 1), 512, nxt, tid);          // issue next tile FIRST
        stage_sw(gb(i + 1), 1024, nxt + 8192, tid);
        compute_tile(cur, cur + 8192, wr, wc, l, acc);  // latency hides under this
        __syncthreads();                              // compiler emits vmcnt(0)+barrier
    }
    compute_tile(lds + 16384, lds + 16384 + 8192, wr, wc, l, acc);
}

// ================= gemm1: [X|H] @ [Wz|Wr]^T -> zgb, rgh (both bf16) =================
__global__ __launch_bounds__(256) void gemm1_k(
    const u16* __restrict__ Xb, const u16* __restrict__ Hb, const u16* __restrict__ Wt,
    const float* __restrict__ ub, const float* __restrict__ rb_,
    u16* __restrict__ zgb, u16* __restrict__ rgh) {
    __shared__ u16 lds[2 * 16384];
    int tid = threadIdx.x;
    int l = tid & 63, w = tid >> 6;
    int wr = w >> 1, wc = w & 1;
    int bidl = blockIdx.x;                       // 0..1023
    int swz = (bidl & 7) * 128 + (bidl >> 3);    // bijective XCD swizzle
    int mb = swz >> 3, nb = swz & 7;
    int m0 = mb * 128;
    int n0 = nb * 128;
    f32x4 acc[4][4];
#pragma unroll
    for (int m = 0; m < 4; ++m)
#pragma unroll
        for (int n = 0; n < 4; ++n) acc[m][n] = (f32x4){0.f, 0.f, 0.f, 0.f};

    auto ga = [&](int t) -> const u16* {
        return (t < 8) ? (Xb + (size_t)m0 * 512 + t * 64)
                       : (Hb + (size_t)m0 * 512 + (t - 8) * 64);
    };
    auto gb = [&](int t) -> const u16* {
        return Wt + (size_t)n0 * 1024 + t * 64;
    };
    kloop(ga, gb, lds, tid, wr, wc, l, acc);

    int colb = n0 + wc * 64;
    int rowb = m0 + wr * 64 + ((l >> 4) << 2);
    bool isZ = n0 < 512;                          // whole block is one gate half
#pragma unroll
    for (int n = 0; n < 4; ++n) {
        int col = colb + n * 16 + (l & 15);
        int c = col & 511;
        float bias = isZ ? ub[c] : rb_[c];
#pragma unroll
        for (int m = 0; m < 4; ++m) {
            int row0 = rowb + m * 16;
#pragma unroll
            for (int r = 0; r < 4; ++r) {
                int row = row0 + r;
                float v = acc[m][n][r] + bias;
                float s = 1.f / (1.f + __expf(-v));
                if (isZ) zgb[(size_t)row * 512 + c] = f2bf(s);
                else     rgh[(size_t)row * 512 + c] = f2bf(s * bf2f(Hb[(size_t)row * 512 + c]));
            }
        }
    }
}

// ================= gemm2: [X|rgh] @ Wh -> ht (f32) =================
__global__ __launch_bounds__(256) void gemm2_k(
    const u16* __restrict__ Xb, const u16* __restrict__ rgh, const u16* __restrict__ Wt,
    const float* __restrict__ hp, const u16* __restrict__ zgb, const float* __restrict__ hb,
    float* __restrict__ out) {
    __shared__ u16 lds[2 * 16384];
    int tid = threadIdx.x;
    int l = tid & 63, w = tid >> 6;
    int wr = w >> 1, wc = w & 1;
    int bidl = blockIdx.x;                        // 0..511
    int swz = (bidl & 7) * 64 + (bidl >> 3);      // bijective XCD swizzle
    int mb = swz >> 2, nb = swz & 3;
    int m0 = mb * 128;
    int n0 = nb * 128;
    f32x4 acc[4][4];
#pragma unroll
    for (int m = 0; m < 4; ++m)
#pragma unroll
        for (int n = 0; n < 4; ++n) acc[m][n] = (f32x4){0.f, 0.f, 0.f, 0.f};

    auto ga = [&](int t) -> const u16* {
        return (t < 8) ? (Xb + (size_t)m0 * 512 + t * 64)
                       : (rgh + (size_t)m0 * 512 + (t - 8) * 64);
    };
    auto gb = [&](int t) -> const u16* {
        return Wt + (size_t)n0 * 1024 + t * 64;
    };
    kloop(ga, gb, lds, tid, wr, wc, l, acc);

    int colb = n0 + wc * 64;
    int rowb = m0 + wr * 64 + ((l >> 4) << 2);
#pragma unroll
    for (int n = 0; n < 4; ++n) {
        int col = colb + n * 16 + (l & 15);
        float bias = hb[col];
#pragma unroll
        for (int m = 0; m < 4; ++m) {
            int row0 = rowb + m * 16;
#pragma unroll
            for (int r = 0; r < 4; ++r) {
                int row = row0 + r;
                float v = acc[m][n][r] + bias;
                float t = fast_tanh(v);
                float h0 = hp[(size_t)row * 512 + col];
                float z = bf2f(zgb[(size_t)row * 512 + col]);
                out[(size_t)row * 512 + col] = h0 + z * (t - h0);
            }
        }
    }
}

extern "C" void kernel_launch(void* const* d_in, const int* in_sizes, int n_in,
                              void* d_out, int out_size, void* d_ws, size_t ws_size,
                              hipStream_t stream) {
    const float* x  = (const float*)d_in[0];
    const float* h  = (const float*)d_in[1];
    const float* wz = (const float*)d_in[2];
    const float* wr = (const float*)d_in[3];
    const float* wh = (const float*)d_in[4];
    const float* ub = (const float*)d_in[5];
    const float* rb = (const float*)d_in[6];
    const float* hb = (const float*)d_in[7];
    float* out = (float*)d_out;

    const int B = 16384;
    char* ws = (char*)d_ws;
    size_t off = 0;
    u16* Xb  = (u16*)(ws + off); off += (size_t)B * 512 * 2;      // 16 MB
    u16* Hb  = (u16*)(ws + off); off += (size_t)B * 512 * 2;      // 16 MB
    u16* Wzr = (u16*)(ws + off); off += (size_t)1024 * 1024 * 2;  // 2 MB
    u16* Wht = (u16*)(ws + off); off += (size_t)512 * 1024 * 2;   // 1 MB
    u16* rgh = (u16*)(ws + off); off += (size_t)B * 512 * 2;      // 16 MB
    u16* zgb = (u16*)(ws + off); off += (size_t)B * 512 * 2;      // 16 MB

    cvt_xh<<<2048, 256, 0, stream>>>(x, h, Xb, Hb, B * 512 / 4);

    dim3 tb(32, 8), tg(16, 32, 3);
    tr_cvt3<<<tg, tb, 0, stream>>>(wz, wr, wh, Wzr, Wzr + (size_t)512 * 1024, Wht);

    gemm1_k<<<1024, 256, 0, stream>>>(Xb, Hb, Wzr, ub, rb, zgb, rgh);
    gemm2_k<<<512, 256, 0, stream>>>(Xb, rgh, Wht, h, zgb, hb, out);
}

// Round 6
// 101.685 us; speedup vs baseline: 1.5472x; 1.1737x over previous
//
#include <hip/hip_runtime.h>
#include <hip/hip_bf16.h>
#include <math.h>

typedef __attribute__((ext_vector_type(4))) float f32x4;
typedef __attribute__((ext_vector_type(8))) float f32x8;
typedef __bf16 bf16x8 __attribute__((ext_vector_type(8)));
typedef unsigned short u16;
typedef u16 u16x8 __attribute__((ext_vector_type(8)));
typedef void __attribute__((address_space(1))) * as1p;
typedef void __attribute__((address_space(3))) * as3p;

__device__ __forceinline__ unsigned short f2bf(float f) {
    union { float f; unsigned int u; } v; v.f = f;
    unsigned int u = v.u;
    u += 0x7fffu + ((u >> 16) & 1u);   // RNE
    return (unsigned short)(u >> 16);
}

__device__ __forceinline__ float bf2f(unsigned short b) {
    union { unsigned int u; float f; } v;
    v.u = ((unsigned int)b) << 16;
    return v.f;
}

__device__ __forceinline__ float fast_tanh(float v) {
    float vc = fminf(fmaxf(v, -15.f), 15.f);
    float e = __expf(2.f * vc);
    return (e - 1.f) / (e + 1.f);
}

// ---------- prepass: fp32 -> bf16 for X, h_prev ----------
__global__ void cvt_xh(const float* __restrict__ x, const float* __restrict__ h,
                       u16* __restrict__ xb, u16* __restrict__ hb, int n4) {
    int i = blockIdx.x * blockDim.x + threadIdx.x;
    int stride = gridDim.x * blockDim.x;
    const float4* x4 = (const float4*)x;
    const float4* h4 = (const float4*)h;
    ushort4* xb4 = (ushort4*)xb;
    ushort4* hb4 = (ushort4*)hb;
    for (; i < n4; i += stride) {
        float4 v = x4[i];
        xb4[i] = make_ushort4(f2bf(v.x), f2bf(v.y), f2bf(v.z), f2bf(v.w));
        float4 w = h4[i];
        hb4[i] = make_ushort4(f2bf(w.x), f2bf(w.y), f2bf(w.z), f2bf(w.w));
    }
}

// ---------- prepass: 3 weight transposes in one launch ----------
__global__ void tr_cvt3(const float* __restrict__ s0, const float* __restrict__ s1,
                        const float* __restrict__ s2, u16* __restrict__ d0,
                        u16* __restrict__ d1, u16* __restrict__ d2) {
    __shared__ float t[32][33];
    const float* src = (blockIdx.z == 0) ? s0 : (blockIdx.z == 1) ? s1 : s2;
    u16* dst = (blockIdx.z == 0) ? d0 : (blockIdx.z == 1) ? d1 : d2;
    int n0 = blockIdx.x * 32;
    int k0 = blockIdx.y * 32;
    int tx = threadIdx.x, ty = threadIdx.y;
#pragma unroll
    for (int i = 0; i < 4; ++i)
        t[ty + i * 8][tx] = src[(size_t)(k0 + ty + i * 8) * 512 + n0 + tx];
    __syncthreads();
#pragma unroll
    for (int i = 0; i < 4; ++i)
        dst[(size_t)(n0 + ty + i * 8) * 1024 + k0 + tx] = f2bf(t[tx][ty + i * 8]);
}

// ---------- staging: 128x64 bf16 tile, linear LDS dest, inverse-swizzled source ----------
__device__ __forceinline__ void stage_sw(const u16* g, int gstride, u16* lds, int tid) {
#pragma unroll
    for (int i = 0; i < 4; ++i) {
        int ob = i * 4096 + ((tid >> 6) << 10);
        int o = ob + ((tid & 63) << 4);
        int row = o >> 7;
        int cb = (o & 127) ^ ((row & 7) << 4);
        const u16* gp = g + (size_t)row * gstride + (cb >> 1);
        __builtin_amdgcn_global_load_lds((as1p)(void*)gp, (as3p)(void*)(lds + (ob >> 1)), 16, 0, 0);
    }
}

// ---------- swizzled LDS fragment read ----------
__device__ __forceinline__ bf16x8 ld_frag(const u16* region, int r, int kb) {
    int byte = (r << 7) + (kb ^ ((r & 7) << 4));
    return *(const bf16x8*)((const char*)region + byte);
}

__device__ __forceinline__ void compute_tile(const u16* LA, const u16* LB,
                                             int wr, int wc, int l, f32x4 (&acc)[4][4]) {
    int fr = l & 15;
    int kbb = (l >> 4) << 4;
#pragma unroll
    for (int q = 0; q < 2; ++q) {
        bf16x8 a[4], b[4];
#pragma unroll
        for (int m = 0; m < 4; ++m)
            a[m] = ld_frag(LA, wr * 64 + m * 16 + fr, q * 64 + kbb);
#pragma unroll
        for (int n = 0; n < 4; ++n)
            b[n] = ld_frag(LB, wc * 64 + n * 16 + fr, q * 64 + kbb);
#pragma unroll
        for (int m = 0; m < 4; ++m)
#pragma unroll
            for (int n = 0; n < 4; ++n)
                acc[m][n] = __builtin_amdgcn_mfma_f32_16x16x32_bf16(a[m], b[n], acc[m][n], 0, 0, 0);
    }
}

// ---------- 2-phase prefetch K-loop (unchanged from round 5) ----------
template<typename AF, typename BF>
__device__ __forceinline__ void kloop(AF ga, BF gb, u16* lds, int tid,
                                      int wr, int wc, int l, f32x4 (&acc)[4][4]) {
    stage_sw(ga(0), 512, lds, tid);
    stage_sw(gb(0), 1024, lds + 8192, tid);
    __syncthreads();
#pragma unroll
    for (int i = 0; i < 15; ++i) {
        u16* nxt = lds + ((i + 1) & 1) * 16384;
        const u16* cur = lds + (i & 1) * 16384;
        stage_sw(ga(i + 1), 512, nxt, tid);
        stage_sw(gb(i + 1), 1024, nxt + 8192, tid);
        compute_tile(cur, cur + 8192, wr, wc, l, acc);
        __syncthreads();
    }
    compute_tile(lds + 16384, lds + 16384 + 8192, wr, wc, l, acc);
}

// ---------- scatter acc into f32 [128][128] LDS tile (re-using k-loop LDS) ----------
__device__ __forceinline__ void scatter_acc(float* tf, const f32x4 (&acc)[4][4],
                                            int wr, int wc, int l) {
    int colb = wc * 64;
    int rowb = wr * 64 + ((l >> 4) << 2);
#pragma unroll
    for (int n = 0; n < 4; ++n) {
        int col = colb + n * 16 + (l & 15);
#pragma unroll
        for (int m = 0; m < 4; ++m) {
            int row0 = rowb + m * 16;
#pragma unroll
            for (int r = 0; r < 4; ++r)
                tf[(row0 + r) * 128 + col] = acc[m][n][r];
        }
    }
}

// ================= gz: [X|H] @ Wz^T -> zgb bf16 =================
__global__ __launch_bounds__(256) void gz_k(
    const u16* __restrict__ Xb, const u16* __restrict__ Hb, const u16* __restrict__ Wt,
    const float* __restrict__ ub, u16* __restrict__ zgb) {
    __shared__ u16 lds[2 * 16384];
    int tid = threadIdx.x;
    int l = tid & 63, w = tid >> 6;
    int wr = w >> 1, wc = w & 1;
    int swz = (blockIdx.x & 7) * 64 + (blockIdx.x >> 3);
    int mb = swz >> 2, nb = swz & 3;
    int m0 = mb * 128, n0 = nb * 128;
    f32x4 acc[4][4];
#pragma unroll
    for (int m = 0; m < 4; ++m)
#pragma unroll
        for (int n = 0; n < 4; ++n) acc[m][n] = (f32x4){0.f, 0.f, 0.f, 0.f};

    auto ga = [&](int t) -> const u16* {
        return (t < 8) ? (Xb + (size_t)m0 * 512 + t * 64)
                       : (Hb + (size_t)m0 * 512 + (t - 8) * 64);
    };
    auto gb = [&](int t) -> const u16* { return Wt + (size_t)n0 * 1024 + t * 64; };
    kloop(ga, gb, lds, tid, wr, wc, l, acc);

    __syncthreads();
    float* tf = (float*)lds;
    scatter_acc(tf, acc, wr, wc, l);
    __syncthreads();
#pragma unroll
    for (int i = 0; i < 8; ++i) {
        int chunk = i * 256 + tid;
        int row = chunk >> 4;
        int c8 = (chunk & 15) << 3;
        const float* src = &tf[row * 128 + c8];
        int gcol = n0 + c8;
        u16x8 o;
#pragma unroll
        for (int j = 0; j < 8; ++j) {
            float v = src[j] + ub[gcol + j];
            o[j] = f2bf(1.f / (1.f + __expf(-v)));
        }
        *(u16x8*)&zgb[(size_t)(m0 + row) * 512 + gcol] = o;
    }
}

// ================= gr: [X|H] @ Wr^T -> rgh = bf16(sigmoid * h) =================
__global__ __launch_bounds__(256) void gr_k(
    const u16* __restrict__ Xb, const u16* __restrict__ Hb, const u16* __restrict__ Wt,
    const float* __restrict__ rb_, u16* __restrict__ rgh) {
    __shared__ u16 lds[2 * 16384];
    int tid = threadIdx.x;
    int l = tid & 63, w = tid >> 6;
    int wr = w >> 1, wc = w & 1;
    int swz = (blockIdx.x & 7) * 64 + (blockIdx.x >> 3);
    int mb = swz >> 2, nb = swz & 3;
    int m0 = mb * 128, n0 = nb * 128;
    f32x4 acc[4][4];
#pragma unroll
    for (int m = 0; m < 4; ++m)
#pragma unroll
        for (int n = 0; n < 4; ++n) acc[m][n] = (f32x4){0.f, 0.f, 0.f, 0.f};

    auto ga = [&](int t) -> const u16* {
        return (t < 8) ? (Xb + (size_t)m0 * 512 + t * 64)
                       : (Hb + (size_t)m0 * 512 + (t - 8) * 64);
    };
    auto gb = [&](int t) -> const u16* { return Wt + (size_t)n0 * 1024 + t * 64; };
    kloop(ga, gb, lds, tid, wr, wc, l, acc);

    __syncthreads();
    float* tf = (float*)lds;
    scatter_acc(tf, acc, wr, wc, l);
    __syncthreads();
#pragma unroll
    for (int i = 0; i < 8; ++i) {
        int chunk = i * 256 + tid;
        int row = chunk >> 4;
        int c8 = (chunk & 15) << 3;
        const float* src = &tf[row * 128 + c8];
        int gcol = n0 + c8;
        size_t gbase = (size_t)(m0 + row) * 512 + gcol;
        u16x8 h8 = *(const u16x8*)&Hb[gbase];
        u16x8 o;
#pragma unroll
        for (int j = 0; j < 8; ++j) {
            float v = src[j] + rb_[gcol + j];
            float s = 1.f / (1.f + __expf(-v));
            o[j] = f2bf(s * bf2f(h8[j]));
        }
        *(u16x8*)&rgh[gbase] = o;
    }
}

// ================= gh: [X|rgh] @ Wh^T -> out fp32 =================
__global__ __launch_bounds__(256) void gh_k(
    const u16* __restrict__ Xb, const u16* __restrict__ rgh, const u16* __restrict__ Wt,
    const float* __restrict__ hp, const u16* __restrict__ zgb, const float* __restrict__ hb,
    float* __restrict__ out) {
    __shared__ u16 lds[2 * 16384];
    int tid = threadIdx.x;
    int l = tid & 63, w = tid >> 6;
    int wr = w >> 1, wc = w & 1;
    int swz = (blockIdx.x & 7) * 64 + (blockIdx.x >> 3);
    int mb = swz >> 2, nb = swz & 3;
    int m0 = mb * 128, n0 = nb * 128;
    f32x4 acc[4][4];
#pragma unroll
    for (int m = 0; m < 4; ++m)
#pragma unroll
        for (int n = 0; n < 4; ++n) acc[m][n] = (f32x4){0.f, 0.f, 0.f, 0.f};

    auto ga = [&](int t) -> const u16* {
        return (t < 8) ? (Xb + (size_t)m0 * 512 + t * 64)
                       : (rgh + (size_t)m0 * 512 + (t - 8) * 64);
    };
    auto gb = [&](int t) -> const u16* { return Wt + (size_t)n0 * 1024 + t * 64; };
    kloop(ga, gb, lds, tid, wr, wc, l, acc);

    __syncthreads();
    float* tf = (float*)lds;
    scatter_acc(tf, acc, wr, wc, l);
    __syncthreads();
#pragma unroll
    for (int i = 0; i < 8; ++i) {
        int chunk = i * 256 + tid;
        int row = chunk >> 4;
        int c8 = (chunk & 15) << 3;
        const float* src = &tf[row * 128 + c8];
        int gcol = n0 + c8;
        size_t gbase = (size_t)(m0 + row) * 512 + gcol;
        f32x8 h8 = *(const f32x8*)&hp[gbase];
        u16x8 z8 = *(const u16x8*)&zgb[gbase];
        f32x8 o;
#pragma unroll
        for (int j = 0; j < 8; ++j) {
            float v = src[j] + hb[gcol + j];
            float t = fast_tanh(v);
            float z = bf2f(z8[j]);
            o[j] = h8[j] + z * (t - h8[j]);
        }
        *(f32x8*)&out[gbase] = o;
    }
}

extern "C" void kernel_launch(void* const* d_in, const int* in_sizes, int n_in,
                              void* d_out, int out_size, void* d_ws, size_t ws_size,
                              hipStream_t stream) {
    const float* x  = (const float*)d_in[0];
    const float* h  = (const float*)d_in[1];
    const float* wz = (const float*)d_in[2];
    const float* wr = (const float*)d_in[3];
    const float* wh = (const float*)d_in[4];
    const float* ub = (const float*)d_in[5];
    const float* rb = (const float*)d_in[6];
    const float* hb = (const float*)d_in[7];
    float* out = (float*)d_out;

    const int B = 16384;
    char* ws = (char*)d_ws;
    size_t off = 0;
    u16* Xb  = (u16*)(ws + off); off += (size_t)B * 512 * 2;      // 16 MB
    u16* Hb  = (u16*)(ws + off); off += (size_t)B * 512 * 2;      // 16 MB
    u16* Wzt = (u16*)(ws + off); off += (size_t)512 * 1024 * 2;   // 1 MB
    u16* Wrt = (u16*)(ws + off); off += (size_t)512 * 1024 * 2;   // 1 MB
    u16* Wht = (u16*)(ws + off); off += (size_t)512 * 1024 * 2;   // 1 MB
    u16* rgh = (u16*)(ws + off); off += (size_t)B * 512 * 2;      // 16 MB
    u16* zgb = (u16*)(ws + off); off += (size_t)B * 512 * 2;      // 16 MB

    cvt_xh<<<2048, 256, 0, stream>>>(x, h, Xb, Hb, B * 512 / 4);

    dim3 tb(32, 8), tg(16, 32, 3);
    tr_cvt3<<<tg, tb, 0, stream>>>(wz, wr, wh, Wzt, Wrt, Wht);

    gz_k<<<512, 256, 0, stream>>>(Xb, Hb, Wzt, ub, zgb);
    gr_k<<<512, 256, 0, stream>>>(Xb, Hb, Wrt, rb, rgh);
    gh_k<<<512, 256, 0, stream>>>(Xb, rgh, Wht, h, zgb, hb, out);
}

// Round 7
// 98.577 us; speedup vs baseline: 1.5959x; 1.0315x over previous
//
#include <hip/hip_runtime.h>
#include <hip/hip_bf16.h>
#include <math.h>

typedef __attribute__((ext_vector_type(4))) float f32x4;
typedef __attribute__((ext_vector_type(8))) float f32x8;
typedef __bf16 bf16x8 __attribute__((ext_vector_type(8)));
typedef unsigned short u16;
typedef u16 u16x8 __attribute__((ext_vector_type(8)));
typedef void __attribute__((address_space(1))) * as1p;
typedef void __attribute__((address_space(3))) * as3p;

__device__ __forceinline__ unsigned short f2bf(float f) {
    union { float f; unsigned int u; } v; v.f = f;
    unsigned int u = v.u;
    u += 0x7fffu + ((u >> 16) & 1u);   // RNE
    return (unsigned short)(u >> 16);
}

__device__ __forceinline__ float bf2f(unsigned short b) {
    union { unsigned int u; float f; } v;
    v.u = ((unsigned int)b) << 16;
    return v.f;
}

__device__ __forceinline__ float fast_tanh(float v) {
    float vc = fminf(fmaxf(v, -15.f), 15.f);
    float e = __expf(2.f * vc);
    return (e - 1.f) / (e + 1.f);
}

// ---------- prepass: fp32 -> bf16 for X, h_prev ----------
__global__ void cvt_xh(const float* __restrict__ x, const float* __restrict__ h,
                       u16* __restrict__ xb, u16* __restrict__ hb, int n4) {
    int i = blockIdx.x * blockDim.x + threadIdx.x;
    int stride = gridDim.x * blockDim.x;
    const float4* x4 = (const float4*)x;
    const float4* h4 = (const float4*)h;
    ushort4* xb4 = (ushort4*)xb;
    ushort4* hb4 = (ushort4*)hb;
    for (; i < n4; i += stride) {
        float4 v = x4[i];
        xb4[i] = make_ushort4(f2bf(v.x), f2bf(v.y), f2bf(v.z), f2bf(v.w));
        float4 w = h4[i];
        hb4[i] = make_ushort4(f2bf(w.x), f2bf(w.y), f2bf(w.z), f2bf(w.w));
    }
}

// ---------- prepass: 3 weight transposes in one launch ----------
__global__ void tr_cvt3(const float* __restrict__ s0, const float* __restrict__ s1,
                        const float* __restrict__ s2, u16* __restrict__ d0,
                        u16* __restrict__ d1, u16* __restrict__ d2) {
    __shared__ float t[32][33];
    const float* src = (blockIdx.z == 0) ? s0 : (blockIdx.z == 1) ? s1 : s2;
    u16* dst = (blockIdx.z == 0) ? d0 : (blockIdx.z == 1) ? d1 : d2;
    int n0 = blockIdx.x * 32;
    int k0 = blockIdx.y * 32;
    int tx = threadIdx.x, ty = threadIdx.y;
#pragma unroll
    for (int i = 0; i < 4; ++i)
        t[ty + i * 8][tx] = src[(size_t)(k0 + ty + i * 8) * 512 + n0 + tx];
    __syncthreads();
#pragma unroll
    for (int i = 0; i < 4; ++i)
        dst[(size_t)(n0 + ty + i * 8) * 1024 + k0 + tx] = f2bf(t[tx][ty + i * 8]);
}

// ================= BK=64 machinery (gr_k, unchanged from round 6) =================
__device__ __forceinline__ void stage_sw(const u16* g, int gstride, u16* lds, int tid) {
#pragma unroll
    for (int i = 0; i < 4; ++i) {
        int ob = i * 4096 + ((tid >> 6) << 10);
        int o = ob + ((tid & 63) << 4);
        int row = o >> 7;
        int cb = (o & 127) ^ ((row & 7) << 4);
        const u16* gp = g + (size_t)row * gstride + (cb >> 1);
        __builtin_amdgcn_global_load_lds((as1p)(void*)gp, (as3p)(void*)(lds + (ob >> 1)), 16, 0, 0);
    }
}

__device__ __forceinline__ bf16x8 ld_frag(const u16* region, int r, int kb) {
    int byte = (r << 7) + (kb ^ ((r & 7) << 4));
    return *(const bf16x8*)((const char*)region + byte);
}

__device__ __forceinline__ void compute_tile(const u16* LA, const u16* LB,
                                             int wr, int wc, int l, f32x4 (&acc)[4][4]) {
    int fr = l & 15;
    int kbb = (l >> 4) << 4;
#pragma unroll
    for (int q = 0; q < 2; ++q) {
        bf16x8 a[4], b[4];
#pragma unroll
        for (int m = 0; m < 4; ++m)
            a[m] = ld_frag(LA, wr * 64 + m * 16 + fr, q * 64 + kbb);
#pragma unroll
        for (int n = 0; n < 4; ++n)
            b[n] = ld_frag(LB, wc * 64 + n * 16 + fr, q * 64 + kbb);
#pragma unroll
        for (int m = 0; m < 4; ++m)
#pragma unroll
            for (int n = 0; n < 4; ++n)
                acc[m][n] = __builtin_amdgcn_mfma_f32_16x16x32_bf16(a[m], b[n], acc[m][n], 0, 0, 0);
    }
}

template<typename AF, typename BF>
__device__ __forceinline__ void kloop(AF ga, BF gb, u16* lds, int tid,
                                      int wr, int wc, int l, f32x4 (&acc)[4][4]) {
    stage_sw(ga(0), 512, lds, tid);
    stage_sw(gb(0), 1024, lds + 8192, tid);
    __syncthreads();
#pragma unroll
    for (int i = 0; i < 15; ++i) {
        u16* nxt = lds + ((i + 1) & 1) * 16384;
        const u16* cur = lds + (i & 1) * 16384;
        stage_sw(ga(i + 1), 512, nxt, tid);
        stage_sw(gb(i + 1), 1024, nxt + 8192, tid);
        compute_tile(cur, cur + 8192, wr, wc, l, acc);
        __syncthreads();
    }
    compute_tile(lds + 16384, lds + 16384 + 8192, wr, wc, l, acc);
}

// ---------- scatter acc into f32 [128][128] LDS tile ----------
__device__ __forceinline__ void scatter_acc(float* tf, const f32x4 (&acc)[4][4],
                                            int wr, int wc, int l) {
    int colb = wc * 64;
    int rowb = wr * 64 + ((l >> 4) << 2);
#pragma unroll
    for (int n = 0; n < 4; ++n) {
        int col = colb + n * 16 + (l & 15);
#pragma unroll
        for (int m = 0; m < 4; ++m) {
            int row0 = rowb + m * 16;
#pragma unroll
            for (int r = 0; r < 4; ++r)
                tf[(row0 + r) * 128 + col] = acc[m][n][r];
        }
    }
}

// ================= gr: [X|H] @ Wr^T -> rgh = bf16(sigmoid * h) =================
__global__ __launch_bounds__(256) void gr_k(
    const u16* __restrict__ Xb, const u16* __restrict__ Hb, const u16* __restrict__ Wt,
    const float* __restrict__ rb_, u16* __restrict__ rgh) {
    __shared__ u16 lds[2 * 16384];
    int tid = threadIdx.x;
    int l = tid & 63, w = tid >> 6;
    int wr = w >> 1, wc = w & 1;
    int swz = (blockIdx.x & 7) * 64 + (blockIdx.x >> 3);
    int mb = swz >> 2, nb = swz & 3;
    int m0 = mb * 128, n0 = nb * 128;
    f32x4 acc[4][4];
#pragma unroll
    for (int m = 0; m < 4; ++m)
#pragma unroll
        for (int n = 0; n < 4; ++n) acc[m][n] = (f32x4){0.f, 0.f, 0.f, 0.f};

    auto ga = [&](int t) -> const u16* {
        return (t < 8) ? (Xb + (size_t)m0 * 512 + t * 64)
                       : (Hb + (size_t)m0 * 512 + (t - 8) * 64);
    };
    auto gb = [&](int t) -> const u16* { return Wt + (size_t)n0 * 1024 + t * 64; };
    kloop(ga, gb, lds, tid, wr, wc, l, acc);

    __syncthreads();
    float* tf = (float*)lds;
    scatter_acc(tf, acc, wr, wc, l);
    __syncthreads();
#pragma unroll
    for (int i = 0; i < 8; ++i) {
        int chunk = i * 256 + tid;
        int row = chunk >> 4;
        int c8 = (chunk & 15) << 3;
        const float* src = &tf[row * 128 + c8];
        int gcol = n0 + c8;
        size_t gbase = (size_t)(m0 + row) * 512 + gcol;
        u16x8 h8 = *(const u16x8*)&Hb[gbase];
        u16x8 o;
#pragma unroll
        for (int j = 0; j < 8; ++j) {
            float v = src[j] + rb_[gcol + j];
            float s = 1.f / (1.f + __expf(-v));
            o[j] = f2bf(s * bf2f(h8[j]));
        }
        *(u16x8*)&rgh[gbase] = o;
    }
}

// ================= BK=32 machinery for the fused kernel =================
// stage 128x32 bf16 (8 KB): linear LDS dest, inverse-swizzled source, 64 B rows
__device__ __forceinline__ void stage32(const u16* g, int gstride, u16* region, int tid) {
#pragma unroll
    for (int i = 0; i < 2; ++i) {
        int ob = i * 4096 + ((tid >> 6) << 10);     // wave-uniform byte base
        int o = ob + ((tid & 63) << 4);
        int row = o >> 6;
        int cb = (o & 63) ^ ((row & 3) << 4);       // inverse swizzle (16B chunks)
        const u16* gp = g + (size_t)row * gstride + (cb >> 1);
        __builtin_amdgcn_global_load_lds((as1p)(void*)gp, (as3p)(void*)(region + (ob >> 1)), 16, 0, 0);
    }
}

__device__ __forceinline__ bf16x8 ld32(const u16* region, int r, int kb) {
    int byte = (r << 6) + (kb ^ ((r & 3) << 4));
    return *(const bf16x8*)((const char*)region + byte);
}

// ================= ghz: fused z-gate + hidden GEMM -> out fp32 =================
// acc_h: [X | rgh] @ Wh^T ; acc_z: [X | H] @ Wz^T   (same 128x128 out-tile)
// LDS per buffer (u16 elems): Ah@0, Az@4096, Bh@8192, Bz@12288; buf stride 16384 (32 KB)
__global__ __launch_bounds__(256, 2) void ghz_k(
    const u16* __restrict__ Xb, const u16* __restrict__ Hb, const u16* __restrict__ rgh,
    const u16* __restrict__ Wht, const u16* __restrict__ Wzt,
    const float* __restrict__ ub, const float* __restrict__ hb,
    float* __restrict__ out) {
    __shared__ u16 lds[2 * 16384];
    int tid = threadIdx.x;
    int l = tid & 63, w = tid >> 6;
    int wr = w >> 1, wc = w & 1;
    int swz = (blockIdx.x & 7) * 64 + (blockIdx.x >> 3);   // bijective XCD swizzle
    int mb = swz >> 2, nb = swz & 3;
    int m0 = mb * 128, n0 = nb * 128;

    f32x4 acc_h[4][4], acc_z[4][4];
#pragma unroll
    for (int m = 0; m < 4; ++m)
#pragma unroll
        for (int n = 0; n < 4; ++n) {
            acc_h[m][n] = (f32x4){0.f, 0.f, 0.f, 0.f};
            acc_z[m][n] = (f32x4){0.f, 0.f, 0.f, 0.f};
        }

    auto ah = [&](int t) -> const u16* {
        return (t < 16) ? (Xb + (size_t)m0 * 512 + t * 32)
                        : (rgh + (size_t)m0 * 512 + (t - 16) * 32);
    };
    auto az = [&](int t) -> const u16* {
        return Hb + (size_t)m0 * 512 + (t - 16) * 32;   // only called for t>=16
    };
    auto bhp = [&](int t) -> const u16* { return Wht + (size_t)n0 * 1024 + t * 32; };
    auto bzp = [&](int t) -> const u16* { return Wzt + (size_t)n0 * 1024 + t * 32; };

    const int fr = l & 15;
    const int kbb = (l >> 4) << 4;   // 16-byte k-group offset

    // prologue: tile 0 (Az aliases Ah since t<16 both read X)
    stage32(ah(0), 512, lds, tid);
    stage32(bhp(0), 1024, lds + 8192, tid);
    stage32(bzp(0), 1024, lds + 12288, tid);
    __syncthreads();

#pragma unroll
    for (int i = 0; i < 32; ++i) {
        const u16* cur = lds + (i & 1) * 16384;
        if (i < 31) {
            u16* nxt = lds + ((i + 1) & 1) * 16384;
            stage32(ah(i + 1), 512, nxt, tid);
            if (i + 1 >= 16) stage32(az(i + 1), 512, nxt + 4096, tid);
            stage32(bhp(i + 1), 1024, nxt + 8192, tid);
            stage32(bzp(i + 1), 1024, nxt + 12288, tid);
        }
        const u16* Ahr = cur;
        const u16* Azr = (i < 16) ? cur : (cur + 4096);
        const u16* Bhr = cur + 8192;
        const u16* Bzr = cur + 12288;
        bf16x8 a[4], azf[4], bh4[4], bz4[4];
#pragma unroll
        for (int m = 0; m < 4; ++m) {
            a[m]   = ld32(Ahr, wr * 64 + m * 16 + fr, kbb);
            azf[m] = ld32(Azr, wr * 64 + m * 16 + fr, kbb);
        }
#pragma unroll
        for (int n = 0; n < 4; ++n) {
            bh4[n] = ld32(Bhr, wc * 64 + n * 16 + fr, kbb);
            bz4[n] = ld32(Bzr, wc * 64 + n * 16 + fr, kbb);
        }
#pragma unroll
        for (int m = 0; m < 4; ++m)
#pragma unroll
            for (int n = 0; n < 4; ++n) {
                acc_h[m][n] = __builtin_amdgcn_mfma_f32_16x16x32_bf16(a[m], bh4[n], acc_h[m][n], 0, 0, 0);
                acc_z[m][n] = __builtin_amdgcn_mfma_f32_16x16x32_bf16(azf[m], bz4[n], acc_z[m][n], 0, 0, 0);
            }
        __syncthreads();
    }

    // ---- epilogue: z pass, then h pass (repack via LDS, coalesced 32B stores) ----
    float* tf = (float*)lds;
    scatter_acc(tf, acc_z, wr, wc, l);
    __syncthreads();
    u16x8 zreg[8];
#pragma unroll
    for (int i = 0; i < 8; ++i) {
        int chunk = i * 256 + tid;
        int row = chunk >> 4;
        int c8 = (chunk & 15) << 3;
        f32x8 vz = *(const f32x8*)&tf[row * 128 + c8];
        f32x8 ubv = *(const f32x8*)&ub[n0 + c8];
#pragma unroll
        for (int j = 0; j < 8; ++j) {
            float s = 1.f / (1.f + __expf(-(vz[j] + ubv[j])));
            zreg[i][j] = f2bf(s);
        }
    }
    __syncthreads();
    scatter_acc(tf, acc_h, wr, wc, l);
    __syncthreads();
#pragma unroll
    for (int i = 0; i < 8; ++i) {
        int chunk = i * 256 + tid;
        int row = chunk >> 4;
        int c8 = (chunk & 15) << 3;
        int gcol = n0 + c8;
        size_t gbase = (size_t)(m0 + row) * 512 + gcol;
        f32x8 vh = *(const f32x8*)&tf[row * 128 + c8];
        f32x8 hbv = *(const f32x8*)&hb[gcol];
        u16x8 h8 = *(const u16x8*)&Hb[gbase];
        f32x8 o;
#pragma unroll
        for (int j = 0; j < 8; ++j) {
            float t = fast_tanh(vh[j] + hbv[j]);
            float h0 = bf2f(h8[j]);
            float z = bf2f(zreg[i][j]);
            o[j] = h0 + z * (t - h0);
        }
        *(f32x8*)&out[gbase] = o;
    }
}

extern "C" void kernel_launch(void* const* d_in, const int* in_sizes, int n_in,
                              void* d_out, int out_size, void* d_ws, size_t ws_size,
                              hipStream_t stream) {
    const float* x  = (const float*)d_in[0];
    const float* h  = (const float*)d_in[1];
    const float* wz = (const float*)d_in[2];
    const float* wr = (const float*)d_in[3];
    const float* wh = (const float*)d_in[4];
    const float* ub = (const float*)d_in[5];
    const float* rb = (const float*)d_in[6];
    const float* hb = (const float*)d_in[7];
    float* out = (float*)d_out;

    const int B = 16384;
    char* ws = (char*)d_ws;
    size_t off = 0;
    u16* Xb  = (u16*)(ws + off); off += (size_t)B * 512 * 2;      // 16 MB
    u16* Hb  = (u16*)(ws + off); off += (size_t)B * 512 * 2;      // 16 MB
    u16* Wzt = (u16*)(ws + off); off += (size_t)512 * 1024 * 2;   // 1 MB
    u16* Wrt = (u16*)(ws + off); off += (size_t)512 * 1024 * 2;   // 1 MB
    u16* Wht = (u16*)(ws + off); off += (size_t)512 * 1024 * 2;   // 1 MB
    u16* rgh = (u16*)(ws + off); off += (size_t)B * 512 * 2;      // 16 MB

    cvt_xh<<<2048, 256, 0, stream>>>(x, h, Xb, Hb, B * 512 / 4);

    dim3 tb(32, 8), tg(16, 32, 3);
    tr_cvt3<<<tg, tb, 0, stream>>>(wz, wr, wh, Wzt, Wrt, Wht);

    gr_k<<<512, 256, 0, stream>>>(Xb, Hb, Wrt, rb, rgh);
    ghz_k<<<512, 256, 0, stream>>>(Xb, Hb, rgh, Wht, Wzt, ub, hb, out);
}